// Round 3
// baseline (937.786 us; speedup 1.0000x reference)
//
#include <hip/hip_runtime.h>
#include <cstdint>
#include <cstddef>

#define N_NODES 50000
#define N_EDGES 800000
#define DIM_H   128
#define DIM_P   64     // propagation width after commuting W3
#define DIM_OUT 1000
#define OUT_PAD 1024   // padded col count for MFMA tiles
#define KHOPS   10
#define BN_EPS  1e-5f

static inline int ceil_div(int a, int b) { return (a + b - 1) / b; }

typedef short  bf16x8  __attribute__((ext_vector_type(8)));
typedef float  floatx4 __attribute__((ext_vector_type(4)));

__device__ __forceinline__ unsigned short f2bf_rne(float v) {
    unsigned int u = __float_as_uint(v);
    return (unsigned short)((u + 0x7fffu + ((u >> 16) & 1u)) >> 16);
}

// ---------------- softmax over att[11] ----------------
__global__ void softmax11(const float* __restrict__ att, float* __restrict__ w) {
    if (threadIdx.x == 0) {
        float mx = att[0];
        for (int i = 1; i < KHOPS + 1; ++i) mx = fmaxf(mx, att[i]);
        float e[KHOPS + 1];
        float s = 0.f;
        for (int i = 0; i < KHOPS + 1; ++i) { e[i] = expf(att[i] - mx); s += e[i]; }
        for (int i = 0; i < KHOPS + 1; ++i) w[i] = e[i] / s;
    }
}

// ---------------- CSR build ----------------
__global__ void count_deg(const int* __restrict__ dst, int* __restrict__ deg, int ne) {
    int i = blockIdx.x * blockDim.x + threadIdx.x;
    if (i < ne) atomicAdd(&deg[dst[i]], 1);
}

// local inclusive scan per 1024-block (shuffle-based, 3 barriers)
__global__ __launch_bounds__(1024) void scan_local(const int* __restrict__ deg,
                                                   int* __restrict__ row_ptr,
                                                   int* __restrict__ bsums, int n) {
    __shared__ int wsum[16];
    const int i = blockIdx.x * 1024 + threadIdx.x;
    const int lane = threadIdx.x & 63, w = threadIdx.x >> 6;
    int v = (i < n) ? deg[i] : 0;
    int s = v;
#pragma unroll
    for (int d = 1; d < 64; d <<= 1) {
        int t = __shfl_up(s, d, 64);
        if (lane >= d) s += t;
    }
    if (lane == 63) wsum[w] = s;
    __syncthreads();
    if (w == 0) {
        int x = (lane < 16) ? wsum[lane] : 0;
#pragma unroll
        for (int d = 1; d < 16; d <<= 1) {
            int t = __shfl_up(x, d, 64);
            if (lane >= d) x += t;
        }
        if (lane < 16) wsum[lane] = x;
    }
    __syncthreads();
    int incl = s + ((w > 0) ? wsum[w - 1] : 0);
    if (i < n) row_ptr[i + 1] = incl;
    if (threadIdx.x == 1023) bsums[blockIdx.x] = incl;
}

// exclusive scan of block sums (nb <= 64), single wave
__global__ void scan_bsums(int* __restrict__ bsums, int nb) {
    int lane = threadIdx.x;
    int v = (lane < nb) ? bsums[lane] : 0;
    int s = v;
#pragma unroll
    for (int d = 1; d < 64; d <<= 1) {
        int t = __shfl_up(s, d, 64);
        if (lane >= d) s += t;
    }
    if (lane < nb) bsums[lane] = s - v;
}

// add block offsets; also derive fill-cursor (exclusive start) in-place in deg
__global__ void scan_finish(int* __restrict__ row_ptr, int* __restrict__ deg,
                            const int* __restrict__ bsums, int n) {
    int i = blockIdx.x * blockDim.x + threadIdx.x;
    if (i < n) {
        int incl = row_ptr[i + 1] + bsums[i >> 10];
        row_ptr[i + 1] = incl;
        deg[i] = incl - deg[i];   // cursor = exclusive prefix
    }
    if (i == 0) row_ptr[0] = 0;
}

__global__ void fill_csr(const int* __restrict__ src, const int* __restrict__ dst,
                         int* __restrict__ cursor, int* __restrict__ col, int ne) {
    int i = blockIdx.x * blockDim.x + threadIdx.x;
    if (i < ne) {
        int d = dst[i];
        int pos = atomicAdd(&cursor[d], 1);
        col[pos] = src[i];
    }
}

// ---------------- fused GEMM: C[n,M] = act(A) @ W (+bias) -------------------
// act(A) row = relu(A*scA+shA)  [if scA]  +  relu(A2*scA2+shA2)  [if A2]
// optional second output C2 = w0p[0] * C  (fused scale_init)
// STATS: per-column (sum, sumsq) accumulated into st[0..M-1], st[M..2M-1]
template<int KD, int CPB, bool STATS>
__global__ __launch_bounds__(256) void gemm_fused(
    const float* __restrict__ A,  const float* __restrict__ scA,
    const float* __restrict__ A2, const float* __restrict__ scA2,
    const float* __restrict__ W,  const float* __restrict__ bias,
    float* __restrict__ C, float* __restrict__ C2, const float* __restrict__ w0p,
    double* __restrict__ st, int n, int M) {
    constexpr int CG  = CPB / 4;     // col groups per block
    constexpr int RG  = 256 / CG;    // row groups
    constexpr int RPT = 64 / RG;     // rows per thread
    __shared__ float As[64][KD + 4];

    const int tid  = threadIdx.x;
    const int cg   = tid % CG;
    const int rg   = tid / CG;
    const int row0 = blockIdx.x * 64;
    const int col0 = blockIdx.y * CPB + cg * 4;

    constexpr int VECS = 64 * KD / 4;
    for (int i = tid; i < VECS; i += 256) {
        int r  = i / (KD / 4);
        int k4 = (i % (KD / 4)) * 4;
        float4 v = make_float4(0.f, 0.f, 0.f, 0.f);
        int row = row0 + r;
        if (row < n) {
            v = *reinterpret_cast<const float4*>(A + (size_t)row * KD + k4);
            if (scA) {
                float4 sc = *reinterpret_cast<const float4*>(scA + k4);
                float4 sh = *reinterpret_cast<const float4*>(scA + KD + k4);
                v.x = fmaxf(v.x * sc.x + sh.x, 0.f);
                v.y = fmaxf(v.y * sc.y + sh.y, 0.f);
                v.z = fmaxf(v.z * sc.z + sh.z, 0.f);
                v.w = fmaxf(v.w * sc.w + sh.w, 0.f);
            }
            if (A2) {
                float4 u  = *reinterpret_cast<const float4*>(A2 + (size_t)row * KD + k4);
                float4 sc = *reinterpret_cast<const float4*>(scA2 + k4);
                float4 sh = *reinterpret_cast<const float4*>(scA2 + KD + k4);
                v.x += fmaxf(u.x * sc.x + sh.x, 0.f);
                v.y += fmaxf(u.y * sc.y + sh.y, 0.f);
                v.z += fmaxf(u.z * sc.z + sh.z, 0.f);
                v.w += fmaxf(u.w * sc.w + sh.w, 0.f);
            }
        }
        *reinterpret_cast<float4*>(&As[r][k4]) = v;
    }
    __syncthreads();

    float acc[RPT][4];
#pragma unroll
    for (int r = 0; r < RPT; ++r)
#pragma unroll
        for (int c = 0; c < 4; ++c) acc[r][c] = 0.f;

    if (col0 < M) {
        for (int k4 = 0; k4 < KD; k4 += 4) {
            float4 w0 = *reinterpret_cast<const float4*>(W + (size_t)(k4 + 0) * M + col0);
            float4 w1 = *reinterpret_cast<const float4*>(W + (size_t)(k4 + 1) * M + col0);
            float4 w2 = *reinterpret_cast<const float4*>(W + (size_t)(k4 + 2) * M + col0);
            float4 w3 = *reinterpret_cast<const float4*>(W + (size_t)(k4 + 3) * M + col0);
#pragma unroll
            for (int r = 0; r < RPT; ++r) {
                float4 a = *reinterpret_cast<const float4*>(&As[rg * RPT + r][k4]);
                acc[r][0] += a.x * w0.x + a.y * w1.x + a.z * w2.x + a.w * w3.x;
                acc[r][1] += a.x * w0.y + a.y * w1.y + a.z * w2.y + a.w * w3.y;
                acc[r][2] += a.x * w0.z + a.y * w1.z + a.z * w2.z + a.w * w3.z;
                acc[r][3] += a.x * w0.w + a.y * w1.w + a.z * w2.w + a.w * w3.w;
            }
        }

        float4 b = make_float4(0.f, 0.f, 0.f, 0.f);
        if (bias) b = *reinterpret_cast<const float4*>(bias + col0);
        const float w0s = C2 ? w0p[0] : 0.f;
#pragma unroll
        for (int r = 0; r < RPT; ++r) {
            int row = row0 + rg * RPT + r;
            if (row < n) {
                float4 o = make_float4(acc[r][0] + b.x, acc[r][1] + b.y,
                                       acc[r][2] + b.z, acc[r][3] + b.w);
                *reinterpret_cast<float4*>(C + (size_t)row * M + col0) = o;
                if (C2) {
                    float4 q = make_float4(w0s * o.x, w0s * o.y, w0s * o.z, w0s * o.w);
                    *reinterpret_cast<float4*>(C2 + (size_t)row * M + col0) = q;
                }
            }
        }
    }

    if (STATS) {
        // per-thread partials over its RPT rows (bias==nullptr for stats layers)
        float s[4] = {0.f, 0.f, 0.f, 0.f}, q[4] = {0.f, 0.f, 0.f, 0.f};
#pragma unroll
        for (int r = 0; r < RPT; ++r) {
            int row = row0 + rg * RPT + r;
            if (row < n) {
#pragma unroll
                for (int c = 0; c < 4; ++c) {
                    float v = acc[r][c];
                    s[c] += v;
                    q[c] += v * v;
                }
            }
        }
        __syncthreads();                    // done with As
        float* sb = &As[0][0];              // [RG][CPB]
        float* qb = sb + RG * CPB;          // [RG][CPB]
#pragma unroll
        for (int c = 0; c < 4; ++c) {
            sb[rg * CPB + cg * 4 + c] = s[c];
            qb[rg * CPB + cg * 4 + c] = q[c];
        }
        __syncthreads();
        if (rg == 0 && col0 < M) {
#pragma unroll
            for (int c = 0; c < 4; ++c) {
                float ts = 0.f, tq = 0.f;
#pragma unroll
                for (int g2 = 0; g2 < RG; ++g2) {
                    ts += sb[g2 * CPB + cg * 4 + c];
                    tq += qb[g2 * CPB + cg * 4 + c];
                }
                atomicAdd(&st[col0 + c], (double)ts);
                atomicAdd(&st[M + col0 + c], (double)tq);
            }
        }
    }
}

// ---------------- BN column stats (sum, sumsq) in double ----------------
template<int M>
__global__ __launch_bounds__(256) void colstats(const float* __restrict__ Z,
                                                double* __restrict__ st, int n) {
    constexpr int RG = 256 / M;
    const int tid = threadIdx.x;
    const int c = tid % M, rg = tid / M;
    double s = 0.0, ss = 0.0;
    for (int row = blockIdx.x * RG + rg; row < n; row += gridDim.x * RG) {
        float v = Z[(size_t)row * M + c];
        s += v;
        ss += (double)v * (double)v;
    }
    __shared__ double sh[2][256];
    sh[0][tid] = s;
    sh[1][tid] = ss;
    __syncthreads();
    if (rg == 0) {
#pragma unroll
        for (int g = 1; g < RG; ++g) { s += sh[0][c + g * M]; ss += sh[1][c + g * M]; }
        atomicAdd(&st[c], s);
        atomicAdd(&st[M + c], ss);
    }
}

__global__ void bn_finalize(const double* __restrict__ st, const float* __restrict__ g,
                            const float* __restrict__ be, float* __restrict__ scsh,
                            int M, int n) {
    int c = threadIdx.x + blockIdx.x * blockDim.x;
    if (c < M) {
        double m = st[c] / n;
        double v = st[M + c] / n - m * m;
        float scale = g[c] * rsqrtf((float)v + BN_EPS);
        scsh[c]     = scale;
        scsh[M + c] = be[c] - (float)m * scale;
    }
}

// ---------------- one propagation hop (CSR gather-sum, no atomics) -----------
// Per node (one wave): ONE col load covers up to 64 edges; indices distributed
// via register shfl; 4 gather instrs (16 edges) issued back-to-back -> short
// dependence chain, 4x memory-level parallelism. 16 lanes x float4 per row.
__global__ __launch_bounds__(256) void propagate(
    const float* __restrict__ cur, float* __restrict__ nxt, float* __restrict__ oacc,
    const int* __restrict__ row_ptr, const int* __restrict__ col,
    const float* __restrict__ wts, int hop, int n) {
    const int node = blockIdx.x * 4 + (threadIdx.x >> 6);
    const int lane = threadIdx.x & 63;
    const int g = lane >> 4;      // neighbor slot 0..3
    const int l = lane & 15;      // feature quad: features l*4 .. l*4+3
    if (node >= n) return;
    const int beg = row_ptr[node], end = row_ptr[node + 1];
    float4 acc = make_float4(0.f, 0.f, 0.f, 0.f);
    for (int base = beg; base < end; base += 64) {
        const int rem = end - base;                    // edges in this window
        int idx = (lane < rem) ? col[base + lane] : 0; // one vmem instr / window
#pragma unroll 1
        for (int p = 0; p < 16 && p * 4 < rem; p += 4) {
            const int e0 = p * 4 + g, e1 = e0 + 4, e2 = e0 + 8, e3 = e0 + 12;
            const int i0 = __shfl(idx, e0, 64);
            const int i1 = __shfl(idx, e1, 64);
            const int i2 = __shfl(idx, e2, 64);
            const int i3 = __shfl(idx, e3, 64);
            float4 v0 = *reinterpret_cast<const float4*>(cur + (size_t)i0 * DIM_P + l * 4);
            float4 v1 = *reinterpret_cast<const float4*>(cur + (size_t)i1 * DIM_P + l * 4);
            float4 v2 = *reinterpret_cast<const float4*>(cur + (size_t)i2 * DIM_P + l * 4);
            float4 v3 = *reinterpret_cast<const float4*>(cur + (size_t)i3 * DIM_P + l * 4);
            const float m0 = (e0 < rem) ? 1.f : 0.f;
            const float m1 = (e1 < rem) ? 1.f : 0.f;
            const float m2 = (e2 < rem) ? 1.f : 0.f;
            const float m3 = (e3 < rem) ? 1.f : 0.f;
            acc.x += v0.x * m0 + v1.x * m1 + v2.x * m2 + v3.x * m3;
            acc.y += v0.y * m0 + v1.y * m1 + v2.y * m2 + v3.y * m3;
            acc.z += v0.z * m0 + v1.z * m1 + v2.z * m2 + v3.z * m3;
            acc.w += v0.w * m0 + v1.w * m1 + v2.w * m2 + v3.w * m3;
        }
    }
#pragma unroll
    for (int off = 16; off < 64; off <<= 1) {
        acc.x += __shfl_xor(acc.x, off, 64);
        acc.y += __shfl_xor(acc.y, off, 64);
        acc.z += __shfl_xor(acc.z, off, 64);
        acc.w += __shfl_xor(acc.w, off, 64);
    }
    if (g == 0) {
        size_t o = (size_t)node * DIM_P + l * 4;
        if (nxt) *reinterpret_cast<float4*>(nxt + o) = acc;
        const float w = wts[hop];
        float4 t = *reinterpret_cast<const float4*>(oacc + o);
        t.x = fmaf(w, acc.x, t.x); t.y = fmaf(w, acc.y, t.y);
        t.z = fmaf(w, acc.z, t.z); t.w = fmaf(w, acc.w, t.w);
        *reinterpret_cast<float4*>(oacc + o) = t;
    }
}

// ---------------- Wout transpose + bf16 convert: WT[c][k] = bf16(W[k][c]) ----
// padded to OUT_PAD rows; pad rows are zero so MFMA tiles past col 999 are inert
__global__ void prep_wout(const float* __restrict__ W, unsigned short* __restrict__ WT) {
    int idx = blockIdx.x * blockDim.x + threadIdx.x;  // idx = c*64 + k
    if (idx < OUT_PAD * DIM_P) {
        int c = idx >> 6, k = idx & 63;
        WT[idx] = (c < DIM_OUT) ? f2bf_rne(W[(size_t)k * DIM_OUT + c]) : (unsigned short)0;
    }
}

// ---------------- bn3 + relu + bf16 convert, once: ABF[row][k] ----------------
__global__ void bn3_relu_bf16(const float* __restrict__ Z, const float* __restrict__ scsh,
                              unsigned short* __restrict__ O) {
    const int total8 = N_NODES * DIM_P / 8;
    int i = blockIdx.x * blockDim.x + threadIdx.x;
    if (i >= total8) return;
    int base = i * 8;
    int c = base & (DIM_P - 1);
    float4 z0 = *reinterpret_cast<const float4*>(Z + base);
    float4 z1 = *reinterpret_cast<const float4*>(Z + base + 4);
    float4 s0 = *reinterpret_cast<const float4*>(scsh + c);
    float4 s1 = *reinterpret_cast<const float4*>(scsh + c + 4);
    float4 h0 = *reinterpret_cast<const float4*>(scsh + DIM_P + c);
    float4 h1 = *reinterpret_cast<const float4*>(scsh + DIM_P + c + 4);
    bf16x8 o;
    o[0] = (short)f2bf_rne(fmaxf(z0.x * s0.x + h0.x, 0.f));
    o[1] = (short)f2bf_rne(fmaxf(z0.y * s0.y + h0.y, 0.f));
    o[2] = (short)f2bf_rne(fmaxf(z0.z * s0.z + h0.z, 0.f));
    o[3] = (short)f2bf_rne(fmaxf(z0.w * s0.w + h0.w, 0.f));
    o[4] = (short)f2bf_rne(fmaxf(z1.x * s1.x + h1.x, 0.f));
    o[5] = (short)f2bf_rne(fmaxf(z1.y * s1.y + h1.y, 0.f));
    o[6] = (short)f2bf_rne(fmaxf(z1.z * s1.z + h1.z, 0.f));
    o[7] = (short)f2bf_rne(fmaxf(z1.w * s1.w + h1.w, 0.f));
    *reinterpret_cast<bf16x8*>(O + base) = o;
}

// ---------------- final GEMM via MFMA: out = ABF @ Wout + bout ----------------
// A-operand = Wout columns (register-resident across row loop), B = node rows.
// Each lane stores float4 of 4 consecutive output columns.
__global__ __launch_bounds__(256, 4) void out_gemm_mfma(
    const unsigned short* __restrict__ ABF, const unsigned short* __restrict__ WT,
    const float* __restrict__ bout, float* __restrict__ out) {
    const int wave = threadIdx.x >> 6;
    const int lane = threadIdx.x & 63;
    const int m    = lane & 15;       // A: out-col within tile; B/D: out-row
    const int quad = lane >> 4;
    const int kb   = quad * 8;
    const int c0   = blockIdx.y * 256 + wave * 64;

    bf16x8 afrag[4][2];
    float4 bias[4];
#pragma unroll
    for (int t = 0; t < 4; ++t) {
        const unsigned short* wrow = WT + (size_t)(c0 + t * 16 + m) * DIM_P;
        afrag[t][0] = *reinterpret_cast<const bf16x8*>(wrow + kb);
        afrag[t][1] = *reinterpret_cast<const bf16x8*>(wrow + 32 + kb);
        int cc = c0 + t * 16 + quad * 4;
        bias[t] = (cc < DIM_OUT) ? *reinterpret_cast<const float4*>(bout + cc)
                                 : make_float4(0.f, 0.f, 0.f, 0.f);
    }

    const int NT = N_NODES / 16;  // 3125 row tiles
    for (int rt = blockIdx.x; rt < NT; rt += gridDim.x) {
        const int row = rt * 16 + m;
        const unsigned short* arow = ABF + (size_t)row * DIM_P;
        bf16x8 bfrag0 = *reinterpret_cast<const bf16x8*>(arow + kb);
        bf16x8 bfrag1 = *reinterpret_cast<const bf16x8*>(arow + 32 + kb);
        float* orow = out + (size_t)row * DIM_OUT;
#pragma unroll
        for (int t = 0; t < 4; ++t) {
            floatx4 acc = {0.f, 0.f, 0.f, 0.f};
            acc = __builtin_amdgcn_mfma_f32_16x16x32_bf16(afrag[t][0], bfrag0, acc, 0, 0, 0);
            acc = __builtin_amdgcn_mfma_f32_16x16x32_bf16(afrag[t][1], bfrag1, acc, 0, 0, 0);
            int cc = c0 + t * 16 + quad * 4;
            if (cc < DIM_OUT) {
                float4 o = make_float4(acc[0] + bias[t].x, acc[1] + bias[t].y,
                                       acc[2] + bias[t].z, acc[3] + bias[t].w);
                *reinterpret_cast<float4*>(orow + cc) = o;
            }
        }
    }
}

// ---------------- launch ----------------
extern "C" void kernel_launch(void* const* d_in, const int* in_sizes, int n_in,
                              void* d_out, int out_size, void* d_ws, size_t ws_size,
                              hipStream_t stream) {
    const float* x    = (const float*)d_in[0];
    const int*   ei   = (const int*)  d_in[1];
    const float* W1   = (const float*)d_in[2];
    const float* g1   = (const float*)d_in[4];
    const float* be1  = (const float*)d_in[5];
    const float* W2   = (const float*)d_in[6];
    const float* g2   = (const float*)d_in[8];
    const float* be2  = (const float*)d_in[9];
    const float* att  = (const float*)d_in[10];
    const float* W3   = (const float*)d_in[11];
    const float* g3   = (const float*)d_in[13];
    const float* be3  = (const float*)d_in[14];
    const float* Wout = (const float*)d_in[15];
    const float* bout = (const float*)d_in[16];
    float* out = (float*)d_out;

    char* base = (char*)d_ws;
    size_t off = 0;
    auto alloc = [&](size_t bytes) -> void* {
        void* r = base + off;
        off += (bytes + 255) & ~(size_t)255;
        return r;
    };
    float*  f0      = (float*) alloc((size_t)N_NODES * DIM_H * 4); // z1
    float*  f1      = (float*) alloc((size_t)N_NODES * DIM_H * 4); // z2
    float*  yb      = (float*) alloc((size_t)N_NODES * DIM_P * 4); // y = act@W3, ping
    float*  tb      = (float*) alloc((size_t)N_NODES * DIM_P * 4); // pong
    float*  oa      = (float*) alloc((size_t)N_NODES * DIM_P * 4); // weighted accumulator
    double* st      = (double*)alloc(640 * 8);
    float*  scsh    = (float*) alloc(768 * 4);
    float*  wts     = (float*) alloc(16 * 4);
    int*    row_ptr = (int*)   alloc((size_t)(N_NODES + 1) * 4);
    int*    deg     = (int*)   alloc((size_t)N_NODES * 4);   // degree -> cursor
    int*    col     = (int*)   alloc((size_t)N_EDGES * 4);
    int*    bsums   = (int*)   alloc(64 * 4);
    unsigned short* WT  = (unsigned short*)alloc((size_t)OUT_PAD * DIM_P * 2);
    unsigned short* ABF = (unsigned short*)alloc((size_t)N_NODES * DIM_P * 2);

    const int* src = ei;
    const int* dst = ei + N_EDGES;
    double* st1 = st;   double* st2 = st + 256; double* st3 = st + 512;
    float*  sc1 = scsh; float*  sc2 = scsh + 256; float* sc3 = scsh + 512;

    hipMemsetAsync(st, 0, 640 * 8, stream);
    hipMemsetAsync(deg, 0, (size_t)N_NODES * 4, stream);

    softmax11<<<1, 64, 0, stream>>>(att, wts);
    prep_wout<<<ceil_div(OUT_PAD * DIM_P, 256), 256, 0, stream>>>(Wout, WT);

    // CSR by destination (fast 3-stage scan)
    count_deg<<<ceil_div(N_EDGES, 256), 256, 0, stream>>>(dst, deg, N_EDGES);
    const int NB = ceil_div(N_NODES, 1024);
    scan_local<<<NB, 1024, 0, stream>>>(deg, row_ptr, bsums, N_NODES);
    scan_bsums<<<1, 64, 0, stream>>>(bsums, NB);
    scan_finish<<<ceil_div(N_NODES, 256), 256, 0, stream>>>(row_ptr, deg, bsums, N_NODES);
    fill_csr<<<ceil_div(N_EDGES, 256), 256, 0, stream>>>(src, dst, deg, col, N_EDGES);

    const int RB = ceil_div(N_NODES, 64);

    // layer 1: z1 = x@W1 ; stats fused (b1 cancels in BN)
    gemm_fused<128, 128, true><<<dim3(RB, 1), 256, 0, stream>>>(
        x, nullptr, nullptr, nullptr, W1, nullptr, f0, nullptr, nullptr, st1,
        N_NODES, DIM_H);
    bn_finalize<<<1, 128, 0, stream>>>(st1, g1, be1, sc1, 128, N_NODES);

    // layer 2: z2 = relu(bn1(z1)) @ W2  (bn1+relu fused into A-staging; stats fused)
    gemm_fused<128, 128, true><<<dim3(RB, 1), 256, 0, stream>>>(
        f0, sc1, nullptr, nullptr, W2, nullptr, f1, nullptr, nullptr, st2,
        N_NODES, DIM_H);
    bn_finalize<<<1, 128, 0, stream>>>(st2, g2, be2, sc2, 128, N_NODES);

    // layer 3 input: h2 = relu(bn2(z2)) + relu(bn1(z1)); y = h2@W3; oa = w0*y
    gemm_fused<128, 64, false><<<dim3(RB, 1), 256, 0, stream>>>(
        f1, sc2, f0, sc1, W3, nullptr, yb, oa, wts, nullptr, N_NODES, DIM_P);

    float* cur = yb;
    float* nxt = tb;
    for (int hop = 1; hop <= KHOPS; ++hop) {
        propagate<<<ceil_div(N_NODES, 4), 256, 0, stream>>>(
            cur, (hop == KHOPS) ? nullptr : nxt, oa, row_ptr, col, wts, hop, N_NODES);
        float* t = cur; cur = nxt; nxt = t;
    }

    // layer 3 BN stats (b3 cancels); then bn3+relu+bf16 applied ONCE
    colstats<64><<<256, 256, 0, stream>>>(oa, st3, N_NODES);
    bn_finalize<<<1, 64, 0, stream>>>(st3, g3, be3, sc3, 64, N_NODES);
    bn3_relu_bf16<<<ceil_div(N_NODES * DIM_P / 8, 256), 256, 0, stream>>>(oa, sc3, ABF);

    // output: out = ABF @ Wout + bout   (bf16 MFMA, column-persistent waves)
    out_gemm_mfma<<<dim3(512, 4), 256, 0, stream>>>(ABF, WT, bout, out);
}

// Round 4
// 873.201 us; speedup vs baseline: 1.0740x; 1.0740x over previous
//
#include <hip/hip_runtime.h>
#include <cstdint>
#include <cstddef>

#define N_NODES 50000
#define N_EDGES 800000
#define DIM_H   128
#define DIM_P   64     // propagation width after commuting W3
#define DIM_OUT 1000
#define OUT_PAD 1024   // padded col count for MFMA tiles
#define KHOPS   10
#define BN_EPS  1e-5f

static inline int ceil_div(int a, int b) { return (a + b - 1) / b; }

typedef short  bf16x8  __attribute__((ext_vector_type(8)));
typedef float  floatx4 __attribute__((ext_vector_type(4)));

__device__ __forceinline__ unsigned short f2bf_rne(float v) {
    unsigned int u = __float_as_uint(v);
    return (unsigned short)((u + 0x7fffu + ((u >> 16) & 1u)) >> 16);
}

// ---------------- softmax over att[11] ----------------
__global__ void softmax11(const float* __restrict__ att, float* __restrict__ w) {
    if (threadIdx.x == 0) {
        float mx = att[0];
        for (int i = 1; i < KHOPS + 1; ++i) mx = fmaxf(mx, att[i]);
        float e[KHOPS + 1];
        float s = 0.f;
        for (int i = 0; i < KHOPS + 1; ++i) { e[i] = expf(att[i] - mx); s += e[i]; }
        for (int i = 0; i < KHOPS + 1; ++i) w[i] = e[i] / s;
    }
}

// ---------------- CSR build ----------------
__global__ void count_deg(const int* __restrict__ dst, int* __restrict__ deg, int ne) {
    int i = blockIdx.x * blockDim.x + threadIdx.x;
    if (i < ne) atomicAdd(&deg[dst[i]], 1);
}

// local inclusive scan per 1024-block (shuffle-based, 3 barriers)
__global__ __launch_bounds__(1024) void scan_local(const int* __restrict__ deg,
                                                   int* __restrict__ row_ptr,
                                                   int* __restrict__ bsums, int n) {
    __shared__ int wsum[16];
    const int i = blockIdx.x * 1024 + threadIdx.x;
    const int lane = threadIdx.x & 63, w = threadIdx.x >> 6;
    int v = (i < n) ? deg[i] : 0;
    int s = v;
#pragma unroll
    for (int d = 1; d < 64; d <<= 1) {
        int t = __shfl_up(s, d, 64);
        if (lane >= d) s += t;
    }
    if (lane == 63) wsum[w] = s;
    __syncthreads();
    if (w == 0) {
        int x = (lane < 16) ? wsum[lane] : 0;
#pragma unroll
        for (int d = 1; d < 16; d <<= 1) {
            int t = __shfl_up(x, d, 64);
            if (lane >= d) x += t;
        }
        if (lane < 16) wsum[lane] = x;
    }
    __syncthreads();
    int incl = s + ((w > 0) ? wsum[w - 1] : 0);
    if (i < n) row_ptr[i + 1] = incl;
    if (threadIdx.x == 1023) bsums[blockIdx.x] = incl;
}

// exclusive scan of block sums (nb <= 64), single wave
__global__ void scan_bsums(int* __restrict__ bsums, int nb) {
    int lane = threadIdx.x;
    int v = (lane < nb) ? bsums[lane] : 0;
    int s = v;
#pragma unroll
    for (int d = 1; d < 64; d <<= 1) {
        int t = __shfl_up(s, d, 64);
        if (lane >= d) s += t;
    }
    if (lane < nb) bsums[lane] = s - v;
}

// add block offsets; also derive fill-cursor (exclusive start) in-place in deg
__global__ void scan_finish(int* __restrict__ row_ptr, int* __restrict__ deg,
                            const int* __restrict__ bsums, int n) {
    int i = blockIdx.x * blockDim.x + threadIdx.x;
    if (i < n) {
        int incl = row_ptr[i + 1] + bsums[i >> 10];
        row_ptr[i + 1] = incl;
        deg[i] = incl - deg[i];   // cursor = exclusive prefix
    }
    if (i == 0) row_ptr[0] = 0;
}

__global__ void fill_csr(const int* __restrict__ src, const int* __restrict__ dst,
                         int* __restrict__ cursor, int* __restrict__ col, int ne) {
    int i = blockIdx.x * blockDim.x + threadIdx.x;
    if (i < ne) {
        int d = dst[i];
        int pos = atomicAdd(&cursor[d], 1);
        col[pos] = src[i];
    }
}

// ---------------- fused GEMM: C[n,M] = act(A) @ W (+bias) -------------------
// act(A) row = relu(A*scA+shA)  [if scA]  +  relu(A2*scA2+shA2)  [if A2]
// optional second output C2 = w0p[0] * C  (fused scale_init)
template<int KD, int CPB>
__global__ __launch_bounds__(256) void gemm_fused(
    const float* __restrict__ A,  const float* __restrict__ scA,
    const float* __restrict__ A2, const float* __restrict__ scA2,
    const float* __restrict__ W,  const float* __restrict__ bias,
    float* __restrict__ C, float* __restrict__ C2, const float* __restrict__ w0p,
    int n, int M) {
    constexpr int CG  = CPB / 4;     // col groups per block
    constexpr int RG  = 256 / CG;    // row groups
    constexpr int RPT = 64 / RG;     // rows per thread
    __shared__ float As[64][KD + 4];

    const int tid  = threadIdx.x;
    const int cg   = tid % CG;
    const int rg   = tid / CG;
    const int row0 = blockIdx.x * 64;
    const int col0 = blockIdx.y * CPB + cg * 4;

    constexpr int VECS = 64 * KD / 4;
    for (int i = tid; i < VECS; i += 256) {
        int r  = i / (KD / 4);
        int k4 = (i % (KD / 4)) * 4;
        float4 v = make_float4(0.f, 0.f, 0.f, 0.f);
        int row = row0 + r;
        if (row < n) {
            v = *reinterpret_cast<const float4*>(A + (size_t)row * KD + k4);
            if (scA) {
                float4 sc = *reinterpret_cast<const float4*>(scA + k4);
                float4 sh = *reinterpret_cast<const float4*>(scA + KD + k4);
                v.x = fmaxf(v.x * sc.x + sh.x, 0.f);
                v.y = fmaxf(v.y * sc.y + sh.y, 0.f);
                v.z = fmaxf(v.z * sc.z + sh.z, 0.f);
                v.w = fmaxf(v.w * sc.w + sh.w, 0.f);
            }
            if (A2) {
                float4 u  = *reinterpret_cast<const float4*>(A2 + (size_t)row * KD + k4);
                float4 sc = *reinterpret_cast<const float4*>(scA2 + k4);
                float4 sh = *reinterpret_cast<const float4*>(scA2 + KD + k4);
                v.x += fmaxf(u.x * sc.x + sh.x, 0.f);
                v.y += fmaxf(u.y * sc.y + sh.y, 0.f);
                v.z += fmaxf(u.z * sc.z + sh.z, 0.f);
                v.w += fmaxf(u.w * sc.w + sh.w, 0.f);
            }
        }
        *reinterpret_cast<float4*>(&As[r][k4]) = v;
    }
    __syncthreads();

    if (col0 >= M) return;

    float acc[RPT][4];
#pragma unroll
    for (int r = 0; r < RPT; ++r)
#pragma unroll
        for (int c = 0; c < 4; ++c) acc[r][c] = 0.f;

    for (int k4 = 0; k4 < KD; k4 += 4) {
        float4 w0 = *reinterpret_cast<const float4*>(W + (size_t)(k4 + 0) * M + col0);
        float4 w1 = *reinterpret_cast<const float4*>(W + (size_t)(k4 + 1) * M + col0);
        float4 w2 = *reinterpret_cast<const float4*>(W + (size_t)(k4 + 2) * M + col0);
        float4 w3 = *reinterpret_cast<const float4*>(W + (size_t)(k4 + 3) * M + col0);
#pragma unroll
        for (int r = 0; r < RPT; ++r) {
            float4 a = *reinterpret_cast<const float4*>(&As[rg * RPT + r][k4]);
            acc[r][0] += a.x * w0.x + a.y * w1.x + a.z * w2.x + a.w * w3.x;
            acc[r][1] += a.x * w0.y + a.y * w1.y + a.z * w2.y + a.w * w3.y;
            acc[r][2] += a.x * w0.z + a.y * w1.z + a.z * w2.z + a.w * w3.z;
            acc[r][3] += a.x * w0.w + a.y * w1.w + a.z * w2.w + a.w * w3.w;
        }
    }

    float4 b = make_float4(0.f, 0.f, 0.f, 0.f);
    if (bias) b = *reinterpret_cast<const float4*>(bias + col0);
    const float w0s = C2 ? w0p[0] : 0.f;
#pragma unroll
    for (int r = 0; r < RPT; ++r) {
        int row = row0 + rg * RPT + r;
        if (row < n) {
            float4 o = make_float4(acc[r][0] + b.x, acc[r][1] + b.y,
                                   acc[r][2] + b.z, acc[r][3] + b.w);
            *reinterpret_cast<float4*>(C + (size_t)row * M + col0) = o;
            if (C2) {
                float4 q = make_float4(w0s * o.x, w0s * o.y, w0s * o.z, w0s * o.w);
                *reinterpret_cast<float4*>(C2 + (size_t)row * M + col0) = q;
            }
        }
    }
}

// ---------------- BN column stats (sum, sumsq) in double ----------------
template<int M>
__global__ __launch_bounds__(256) void colstats(const float* __restrict__ Z,
                                                double* __restrict__ st, int n) {
    constexpr int RG = 256 / M;
    const int tid = threadIdx.x;
    const int c = tid % M, rg = tid / M;
    double s = 0.0, ss = 0.0;
    for (int row = blockIdx.x * RG + rg; row < n; row += gridDim.x * RG) {
        float v = Z[(size_t)row * M + c];
        s += v;
        ss += (double)v * (double)v;
    }
    __shared__ double sh[2][256];
    sh[0][tid] = s;
    sh[1][tid] = ss;
    __syncthreads();
    if (rg == 0) {
#pragma unroll
        for (int g = 1; g < RG; ++g) { s += sh[0][c + g * M]; ss += sh[1][c + g * M]; }
        atomicAdd(&st[c], s);
        atomicAdd(&st[M + c], ss);
    }
}

__global__ void bn_finalize(const double* __restrict__ st, const float* __restrict__ g,
                            const float* __restrict__ be, float* __restrict__ scsh,
                            int M, int n) {
    int c = threadIdx.x + blockIdx.x * blockDim.x;
    if (c < M) {
        double m = st[c] / n;
        double v = st[M + c] / n - m * m;
        float scale = g[c] * rsqrtf((float)v + BN_EPS);
        scsh[c]     = scale;
        scsh[M + c] = be[c] - (float)m * scale;
    }
}

// ---------------- one propagation hop (CSR gather-sum, no atomics) -----------
// 16 lanes x float4 cover one 256B neighbor row; 4 lane-groups process 4
// neighbors per wave vmem instruction (1KB/instr). Main loop: 4 col loads +
// 4 gathers back-to-back = 16 edges in flight (one chain per 16 edges).
// Tails at 8/4/1 granularity (no wasted masked gathers).
__global__ __launch_bounds__(256) void propagate(
    const float* __restrict__ cur, float* __restrict__ nxt, float* __restrict__ oacc,
    const int* __restrict__ row_ptr, const int* __restrict__ col,
    const float* __restrict__ wts, int hop, int n) {
    const int node = blockIdx.x * 4 + (threadIdx.x >> 6);
    const int lane = threadIdx.x & 63;
    const int g = lane >> 4;      // neighbor slot 0..3
    const int l = lane & 15;      // feature quad: features l*4 .. l*4+3
    if (node >= n) return;
    const int beg = row_ptr[node], end = row_ptr[node + 1];
    float4 acc = make_float4(0.f, 0.f, 0.f, 0.f);
    int e = beg;
    for (; e + 16 <= end; e += 16) {
        int s0 = col[e + g];
        int s1 = col[e + g + 4];
        int s2 = col[e + g + 8];
        int s3 = col[e + g + 12];
        float4 v0 = *reinterpret_cast<const float4*>(cur + (size_t)s0 * DIM_P + l * 4);
        float4 v1 = *reinterpret_cast<const float4*>(cur + (size_t)s1 * DIM_P + l * 4);
        float4 v2 = *reinterpret_cast<const float4*>(cur + (size_t)s2 * DIM_P + l * 4);
        float4 v3 = *reinterpret_cast<const float4*>(cur + (size_t)s3 * DIM_P + l * 4);
        acc.x += (v0.x + v1.x) + (v2.x + v3.x);
        acc.y += (v0.y + v1.y) + (v2.y + v3.y);
        acc.z += (v0.z + v1.z) + (v2.z + v3.z);
        acc.w += (v0.w + v1.w) + (v2.w + v3.w);
    }
    if (e + 8 <= end) {
        int s0 = col[e + g];
        int s1 = col[e + g + 4];
        float4 v0 = *reinterpret_cast<const float4*>(cur + (size_t)s0 * DIM_P + l * 4);
        float4 v1 = *reinterpret_cast<const float4*>(cur + (size_t)s1 * DIM_P + l * 4);
        acc.x += v0.x + v1.x; acc.y += v0.y + v1.y;
        acc.z += v0.z + v1.z; acc.w += v0.w + v1.w;
        e += 8;
    }
    if (e + 4 <= end) {
        int s = col[e + g];
        float4 v = *reinterpret_cast<const float4*>(cur + (size_t)s * DIM_P + l * 4);
        acc.x += v.x; acc.y += v.y; acc.z += v.z; acc.w += v.w;
        e += 4;
    }
    if (e + g < end) {
        int s = col[e + g];
        float4 v = *reinterpret_cast<const float4*>(cur + (size_t)s * DIM_P + l * 4);
        acc.x += v.x; acc.y += v.y; acc.z += v.z; acc.w += v.w;
    }
#pragma unroll
    for (int off = 16; off < 64; off <<= 1) {
        acc.x += __shfl_xor(acc.x, off, 64);
        acc.y += __shfl_xor(acc.y, off, 64);
        acc.z += __shfl_xor(acc.z, off, 64);
        acc.w += __shfl_xor(acc.w, off, 64);
    }
    if (g == 0) {
        size_t o = (size_t)node * DIM_P + l * 4;
        if (nxt) *reinterpret_cast<float4*>(nxt + o) = acc;
        const float w = wts[hop];
        float4 t = *reinterpret_cast<const float4*>(oacc + o);
        t.x = fmaf(w, acc.x, t.x); t.y = fmaf(w, acc.y, t.y);
        t.z = fmaf(w, acc.z, t.z); t.w = fmaf(w, acc.w, t.w);
        *reinterpret_cast<float4*>(oacc + o) = t;
    }
}

// ---------------- Wout transpose + bf16 convert: WT[c][k] = bf16(W[k][c]) ----
// padded to OUT_PAD rows; pad rows are zero so MFMA tiles past col 999 are inert
__global__ void prep_wout(const float* __restrict__ W, unsigned short* __restrict__ WT) {
    int idx = blockIdx.x * blockDim.x + threadIdx.x;  // idx = c*64 + k
    if (idx < OUT_PAD * DIM_P) {
        int c = idx >> 6, k = idx & 63;
        WT[idx] = (c < DIM_OUT) ? f2bf_rne(W[(size_t)k * DIM_OUT + c]) : (unsigned short)0;
    }
}

// ---------------- bn3 + relu + bf16 convert, once: ABF[row][k] ----------------
__global__ void bn3_relu_bf16(const float* __restrict__ Z, const float* __restrict__ scsh,
                              unsigned short* __restrict__ O) {
    const int total8 = N_NODES * DIM_P / 8;
    int i = blockIdx.x * blockDim.x + threadIdx.x;
    if (i >= total8) return;
    int base = i * 8;
    int c = base & (DIM_P - 1);
    float4 z0 = *reinterpret_cast<const float4*>(Z + base);
    float4 z1 = *reinterpret_cast<const float4*>(Z + base + 4);
    float4 s0 = *reinterpret_cast<const float4*>(scsh + c);
    float4 s1 = *reinterpret_cast<const float4*>(scsh + c + 4);
    float4 h0 = *reinterpret_cast<const float4*>(scsh + DIM_P + c);
    float4 h1 = *reinterpret_cast<const float4*>(scsh + DIM_P + c + 4);
    bf16x8 o;
    o[0] = (short)f2bf_rne(fmaxf(z0.x * s0.x + h0.x, 0.f));
    o[1] = (short)f2bf_rne(fmaxf(z0.y * s0.y + h0.y, 0.f));
    o[2] = (short)f2bf_rne(fmaxf(z0.z * s0.z + h0.z, 0.f));
    o[3] = (short)f2bf_rne(fmaxf(z0.w * s0.w + h0.w, 0.f));
    o[4] = (short)f2bf_rne(fmaxf(z1.x * s1.x + h1.x, 0.f));
    o[5] = (short)f2bf_rne(fmaxf(z1.y * s1.y + h1.y, 0.f));
    o[6] = (short)f2bf_rne(fmaxf(z1.z * s1.z + h1.z, 0.f));
    o[7] = (short)f2bf_rne(fmaxf(z1.w * s1.w + h1.w, 0.f));
    *reinterpret_cast<bf16x8*>(O + base) = o;
}

// ---------------- final GEMM via MFMA: out = ABF @ Wout + bout ----------------
// A-operand = Wout columns (register-resident across row loop), B = node rows.
// Each lane stores float4 of 4 consecutive output columns.
__global__ __launch_bounds__(256, 4) void out_gemm_mfma(
    const unsigned short* __restrict__ ABF, const unsigned short* __restrict__ WT,
    const float* __restrict__ bout, float* __restrict__ out) {
    const int wave = threadIdx.x >> 6;
    const int lane = threadIdx.x & 63;
    const int m    = lane & 15;       // A: out-col within tile; B/D: out-row
    const int quad = lane >> 4;
    const int kb   = quad * 8;
    const int c0   = blockIdx.y * 256 + wave * 64;

    bf16x8 afrag[4][2];
    float4 bias[4];
#pragma unroll
    for (int t = 0; t < 4; ++t) {
        const unsigned short* wrow = WT + (size_t)(c0 + t * 16 + m) * DIM_P;
        afrag[t][0] = *reinterpret_cast<const bf16x8*>(wrow + kb);
        afrag[t][1] = *reinterpret_cast<const bf16x8*>(wrow + 32 + kb);
        int cc = c0 + t * 16 + quad * 4;
        bias[t] = (cc < DIM_OUT) ? *reinterpret_cast<const float4*>(bout + cc)
                                 : make_float4(0.f, 0.f, 0.f, 0.f);
    }

    const int NT = N_NODES / 16;  // 3125 row tiles
    for (int rt = blockIdx.x; rt < NT; rt += gridDim.x) {
        const int row = rt * 16 + m;
        const unsigned short* arow = ABF + (size_t)row * DIM_P;
        bf16x8 bfrag0 = *reinterpret_cast<const bf16x8*>(arow + kb);
        bf16x8 bfrag1 = *reinterpret_cast<const bf16x8*>(arow + 32 + kb);
        float* orow = out + (size_t)row * DIM_OUT;
#pragma unroll
        for (int t = 0; t < 4; ++t) {
            floatx4 acc = {0.f, 0.f, 0.f, 0.f};
            acc = __builtin_amdgcn_mfma_f32_16x16x32_bf16(afrag[t][0], bfrag0, acc, 0, 0, 0);
            acc = __builtin_amdgcn_mfma_f32_16x16x32_bf16(afrag[t][1], bfrag1, acc, 0, 0, 0);
            int cc = c0 + t * 16 + quad * 4;
            if (cc < DIM_OUT) {
                float4 o = make_float4(acc[0] + bias[t].x, acc[1] + bias[t].y,
                                       acc[2] + bias[t].z, acc[3] + bias[t].w);
                *reinterpret_cast<float4*>(orow + cc) = o;
            }
        }
    }
}

// ---------------- launch ----------------
extern "C" void kernel_launch(void* const* d_in, const int* in_sizes, int n_in,
                              void* d_out, int out_size, void* d_ws, size_t ws_size,
                              hipStream_t stream) {
    const float* x    = (const float*)d_in[0];
    const int*   ei   = (const int*)  d_in[1];
    const float* W1   = (const float*)d_in[2];
    const float* g1   = (const float*)d_in[4];
    const float* be1  = (const float*)d_in[5];
    const float* W2   = (const float*)d_in[6];
    const float* g2   = (const float*)d_in[8];
    const float* be2  = (const float*)d_in[9];
    const float* att  = (const float*)d_in[10];
    const float* W3   = (const float*)d_in[11];
    const float* g3   = (const float*)d_in[13];
    const float* be3  = (const float*)d_in[14];
    const float* Wout = (const float*)d_in[15];
    const float* bout = (const float*)d_in[16];
    float* out = (float*)d_out;

    char* base = (char*)d_ws;
    size_t off = 0;
    auto alloc = [&](size_t bytes) -> void* {
        void* r = base + off;
        off += (bytes + 255) & ~(size_t)255;
        return r;
    };
    float*  f0      = (float*) alloc((size_t)N_NODES * DIM_H * 4); // z1
    float*  f1      = (float*) alloc((size_t)N_NODES * DIM_H * 4); // z2
    float*  yb      = (float*) alloc((size_t)N_NODES * DIM_P * 4); // y = act@W3, ping
    float*  tb      = (float*) alloc((size_t)N_NODES * DIM_P * 4); // pong
    float*  oa      = (float*) alloc((size_t)N_NODES * DIM_P * 4); // weighted accumulator
    double* st      = (double*)alloc(640 * 8);
    float*  scsh    = (float*) alloc(768 * 4);
    float*  wts     = (float*) alloc(16 * 4);
    int*    row_ptr = (int*)   alloc((size_t)(N_NODES + 1) * 4);
    int*    deg     = (int*)   alloc((size_t)N_NODES * 4);   // degree -> cursor
    int*    col     = (int*)   alloc((size_t)N_EDGES * 4);
    int*    bsums   = (int*)   alloc(64 * 4);
    unsigned short* WT  = (unsigned short*)alloc((size_t)OUT_PAD * DIM_P * 2);
    unsigned short* ABF = (unsigned short*)alloc((size_t)N_NODES * DIM_P * 2);

    const int* src = ei;
    const int* dst = ei + N_EDGES;
    double* st1 = st;   double* st2 = st + 256; double* st3 = st + 512;
    float*  sc1 = scsh; float*  sc2 = scsh + 256; float* sc3 = scsh + 512;

    hipMemsetAsync(st, 0, 640 * 8, stream);
    hipMemsetAsync(deg, 0, (size_t)N_NODES * 4, stream);

    softmax11<<<1, 64, 0, stream>>>(att, wts);
    prep_wout<<<ceil_div(OUT_PAD * DIM_P, 256), 256, 0, stream>>>(Wout, WT);

    // CSR by destination (fast 3-stage scan)
    count_deg<<<ceil_div(N_EDGES, 256), 256, 0, stream>>>(dst, deg, N_EDGES);
    const int NB = ceil_div(N_NODES, 1024);
    scan_local<<<NB, 1024, 0, stream>>>(deg, row_ptr, bsums, N_NODES);
    scan_bsums<<<1, 64, 0, stream>>>(bsums, NB);
    scan_finish<<<ceil_div(N_NODES, 256), 256, 0, stream>>>(row_ptr, deg, bsums, N_NODES);
    fill_csr<<<ceil_div(N_EDGES, 256), 256, 0, stream>>>(src, dst, deg, col, N_EDGES);

    const int RB = ceil_div(N_NODES, 64);

    // layer 1: z1 = x@W1 ; stats (b1 cancels in BN)
    gemm_fused<128, 128><<<dim3(RB, 1), 256, 0, stream>>>(
        x, nullptr, nullptr, nullptr, W1, nullptr, f0, nullptr, nullptr, N_NODES, DIM_H);
    colstats<128><<<256, 256, 0, stream>>>(f0, st1, N_NODES);
    bn_finalize<<<1, 128, 0, stream>>>(st1, g1, be1, sc1, 128, N_NODES);

    // layer 2: z2 = relu(bn1(z1)) @ W2  (bn1+relu fused into A-staging)
    gemm_fused<128, 128><<<dim3(RB, 1), 256, 0, stream>>>(
        f0, sc1, nullptr, nullptr, W2, nullptr, f1, nullptr, nullptr, N_NODES, DIM_H);
    colstats<128><<<256, 256, 0, stream>>>(f1, st2, N_NODES);
    bn_finalize<<<1, 128, 0, stream>>>(st2, g2, be2, sc2, 128, N_NODES);

    // layer 3 input: h2 = relu(bn2(z2)) + relu(bn1(z1)); y = h2@W3; oa = w0*y
    gemm_fused<128, 64><<<dim3(RB, 1), 256, 0, stream>>>(
        f1, sc2, f0, sc1, W3, nullptr, yb, oa, wts, N_NODES, DIM_P);

    float* cur = yb;
    float* nxt = tb;
    for (int hop = 1; hop <= KHOPS; ++hop) {
        propagate<<<ceil_div(N_NODES, 4), 256, 0, stream>>>(
            cur, (hop == KHOPS) ? nullptr : nxt, oa, row_ptr, col, wts, hop, N_NODES);
        float* t = cur; cur = nxt; nxt = t;
    }

    // layer 3 BN stats (b3 cancels); then bn3+relu+bf16 applied ONCE
    colstats<64><<<256, 256, 0, stream>>>(oa, st3, N_NODES);
    bn_finalize<<<1, 64, 0, stream>>>(st3, g3, be3, sc3, 64, N_NODES);
    bn3_relu_bf16<<<ceil_div(N_NODES * DIM_P / 8, 256), 256, 0, stream>>>(oa, sc3, ABF);

    // output: out = ABF @ Wout + bout   (bf16 MFMA, column-persistent waves)
    out_gemm_mfma<<<dim3(512, 4), 256, 0, stream>>>(ABF, WT, bout, out);
}